// Round 2
// baseline (339.382 us; speedup 1.0000x reference)
//
#include <hip/hip_runtime.h>
#include <hip/hip_bf16.h>
#include <math.h>

// ---------------------------------------------------------------------------
// 3-layer GAT (PyG GATConv semantics, self-loops, eval mode).
// Pipeline per call:
//   CSR build (count -> 1-block scan -> fill, keeps esrc+edst in CSR order)
//   per layer: GEMM (f32 vector; no fp32 MFMA on CDNA4)
//              logits (als/ald per (node,head) + fused self-loop logit)
//              edge_e (per-edge leaky-relu logit, CSR order -> sequential)
//              gather (two-pass softmax: max pass, then exp-sum pass; exp and
//                      HF loads are NOT loop-carried; esrc/evals prefetched)
// ---------------------------------------------------------------------------

#define NEG_SLOPE 0.2f

// ---------------- CSR build ----------------

__global__ __launch_bounds__(256) void count_deg(const int* __restrict__ ei,
                                                 int* __restrict__ deg, int E) {
  int e = blockIdx.x * blockDim.x + threadIdx.x;
  if (e < E) atomicAdd(&deg[ei[E + e]], 1);  // ei[E+e] = dst
}

__global__ __launch_bounds__(1024) void scan_k(const int* __restrict__ deg,
                                               int* __restrict__ rowptr,
                                               int* __restrict__ cursor, int n) {
  __shared__ int part[1024];
  int t = threadIdx.x;
  int chunk = (n + 1023) >> 10;
  int lo = t * chunk;
  int hi = min(lo + chunk, n);
  int s = 0;
  for (int i = lo; i < hi; ++i) s += deg[i];
  part[t] = s;
  __syncthreads();
  for (int off = 1; off < 1024; off <<= 1) {
    int v = (t >= off) ? part[t - off] : 0;
    __syncthreads();
    part[t] += v;
    __syncthreads();
  }
  int run = (t == 0) ? 0 : part[t - 1];
  for (int i = lo; i < hi; ++i) {
    rowptr[i] = run;
    cursor[i] = run;
    run += deg[i];
  }
  if (t == 1023) rowptr[n] = part[1023];
}

__global__ __launch_bounds__(256) void fill_edges(const int* __restrict__ ei,
                                                  int* __restrict__ cursor,
                                                  int* __restrict__ esrc,
                                                  int* __restrict__ edst, int E) {
  int e = blockIdx.x * blockDim.x + threadIdx.x;
  if (e < E) {
    int d = ei[E + e];
    int pos = atomicAdd(&cursor[d], 1);
    esrc[pos] = ei[e];  // src
    edst[pos] = d;
  }
}

// ---------------- GEMM: H[n,N] = X[n,K] @ W[K,N] ----------------
// Per-thread 8 cols (layer 1: small).
template <int K, int N>
__global__ __launch_bounds__(256) void gemm8(const float* __restrict__ X,
                                             const float* __restrict__ W,
                                             float* __restrict__ H, int n) {
  int idx = blockIdx.x * blockDim.x + threadIdx.x;
  constexpr int PER = N / 8;
  int node = idx / PER;
  int c0 = (idx % PER) * 8;
  if (node >= n) return;
  float a0 = 0.f, a1 = 0.f, a2 = 0.f, a3 = 0.f, a4 = 0.f, a5 = 0.f, a6 = 0.f, a7 = 0.f;
  const float* xr = X + (size_t)node * K;
#pragma unroll 4
  for (int k = 0; k < K; ++k) {
    float xv = xr[k];
    const float4 w0 = *reinterpret_cast<const float4*>(&W[(size_t)k * N + c0]);
    const float4 w1 = *reinterpret_cast<const float4*>(&W[(size_t)k * N + c0 + 4]);
    a0 += xv * w0.x; a1 += xv * w0.y; a2 += xv * w0.z; a3 += xv * w0.w;
    a4 += xv * w1.x; a5 += xv * w1.y; a6 += xv * w1.z; a7 += xv * w1.w;
  }
  float4* o = reinterpret_cast<float4*>(&H[(size_t)node * N + c0]);
  o[0] = make_float4(a0, a1, a2, a3);
  o[1] = make_float4(a4, a5, a6, a7);
}

// Wave-per-node-group GEMM (layer 2): 64 lanes cover N=512 cols (8 each);
// NB nodes per wave reuse every W row -> W L2 traffic / NB.
template <int K, int N, int NB>
__global__ __launch_bounds__(64) void gemm_nb(const float* __restrict__ X,
                                              const float* __restrict__ W,
                                              float* __restrict__ H, int n) {
  int node0 = blockIdx.x * NB;
  int c0 = threadIdx.x * 8;
  if (node0 >= n) return;
  float acc[NB][8];
#pragma unroll
  for (int j = 0; j < NB; ++j)
#pragma unroll
    for (int c = 0; c < 8; ++c) acc[j][c] = 0.f;
  for (int k = 0; k < K; ++k) {
    const float4 w0 = *reinterpret_cast<const float4*>(&W[(size_t)k * N + c0]);
    const float4 w1 = *reinterpret_cast<const float4*>(&W[(size_t)k * N + c0 + 4]);
#pragma unroll
    for (int j = 0; j < NB; ++j) {
      int nd = node0 + j;
      if (NB > 1 && nd >= n) nd = n - 1;  // clamp (writes guarded below)
      float xv = X[(size_t)nd * K + k];
      acc[j][0] += xv * w0.x; acc[j][1] += xv * w0.y;
      acc[j][2] += xv * w0.z; acc[j][3] += xv * w0.w;
      acc[j][4] += xv * w1.x; acc[j][5] += xv * w1.y;
      acc[j][6] += xv * w1.z; acc[j][7] += xv * w1.w;
    }
  }
#pragma unroll
  for (int j = 0; j < NB; ++j) {
    int nd = node0 + j;
    if (nd >= n) break;
    float4* o = reinterpret_cast<float4*>(&H[(size_t)nd * N + c0]);
    o[0] = make_float4(acc[j][0], acc[j][1], acc[j][2], acc[j][3]);
    o[1] = make_float4(acc[j][4], acc[j][5], acc[j][6], acc[j][7]);
  }
}

// Layer-3 GEMM: X[n,512] @ W[512,6]. One wave per node, lane-split K,
// shuffle reduction (coalesced X reads; W3 12 KB L1-resident).
__global__ __launch_bounds__(64) void gemm_l3(const float* __restrict__ X,
                                              const float* __restrict__ W,
                                              float* __restrict__ H, int n) {
  int node = blockIdx.x;
  int lane = threadIdx.x;
  if (node >= n) return;
  float acc[6] = {0.f, 0.f, 0.f, 0.f, 0.f, 0.f};
  for (int k = lane; k < 512; k += 64) {
    float xv = X[(size_t)node * 512 + k];
#pragma unroll
    for (int c = 0; c < 6; ++c) acc[c] += xv * W[k * 6 + c];
  }
#pragma unroll
  for (int c = 0; c < 6; ++c) {
    float v = acc[c];
    for (int off = 32; off >= 1; off >>= 1) v += __shfl_down(v, off, 64);
    if (lane == 0) H[(size_t)node * 6 + c] = v;
  }
}

// ---------------- logits: als/ald per (node,head) + self-loop logit ----------

template <int HH, int C>
__global__ __launch_bounds__(256) void logits_k(const float* __restrict__ HF,
                                                const float* __restrict__ Asrc,
                                                const float* __restrict__ Adst,
                                                float* __restrict__ als,
                                                float* __restrict__ ald,
                                                float* __restrict__ selfe, int n) {
  int idx = blockIdx.x * blockDim.x + threadIdx.x;
  if (idx >= n * HH) return;
  int node = idx / HH;
  int h = idx - node * HH;
  const float* f = HF + (size_t)node * HH * C + h * C;
  float s0 = 0.f, s1 = 0.f;
#pragma unroll
  for (int c = 0; c < C; ++c) {
    float v = f[c];
    s0 += v * Asrc[h * C + c];
    s1 += v * Adst[h * C + c];
  }
  als[idx] = s0;
  ald[idx] = s1;
  float e = s0 + s1;
  selfe[idx] = e > 0.f ? e : NEG_SLOPE * e;
}

// ---------------- per-edge logits (CSR order -> sequential in gather) -------

template <int HH>
__global__ __launch_bounds__(256) void edge_e(const int* __restrict__ esrc,
                                              const int* __restrict__ edst,
                                              const float* __restrict__ als,
                                              const float* __restrict__ ald,
                                              float* __restrict__ evals, int E) {
  int e = blockIdx.x * blockDim.x + threadIdx.x;
  if (e >= E) return;
  int s = esrc[e], d = edst[e];
#pragma unroll
  for (int h = 0; h < HH; ++h) {
    float v = als[(size_t)s * HH + h] + ald[(size_t)d * HH + h];
    evals[(size_t)e * HH + h] = v > 0.f ? v : NEG_SLOPE * v;
  }
}

// ---------------- gather: two-pass softmax + weighted aggregate -------------
// HH heads total, C ch/head, HPW heads per wave. lane -> (hg=lane/C, ch=lane%C).

template <int HH, int C, int HPW, bool DO_ELU>
__global__ __launch_bounds__(256) void gather_k(
    const float* __restrict__ HF, const float* __restrict__ evals,
    const float* __restrict__ selfe, const float* __restrict__ bias,
    const int* __restrict__ rowptr, const int* __restrict__ esrc,
    float* __restrict__ OUT, int n) {
  int gtid = blockIdx.x * blockDim.x + threadIdx.x;
  int w = gtid >> 6;
  int lane = gtid & 63;
  constexpr int WPN = HH / HPW;  // waves per node
  int node = w / WPN;
  if (node >= n) return;
  int hb = (w - node * WPN) * HPW;
  int hg = lane / C;
  int ch = lane - hg * C;
  bool act = hg < HPW;
  if (!act) { hg = 0; ch = 0; }
  int h = hb + hg;

  int r0 = rowptr[node];
  int r1 = rowptr[node + 1];
  float e0 = selfe[(size_t)node * HH + h];

  // pass 1: row max (fmax chain only; loads independent)
  float m = e0;
  for (int p = r0; p < r1; ++p) m = fmaxf(m, evals[(size_t)p * HH + h]);

  // pass 2: exp-sum + weighted aggregate; exp NOT loop-carried;
  // esrc/evals prefetched one iteration ahead.
  float pv0 = __expf(e0 - m);
  float s = pv0;
  float acc = pv0 * HF[(size_t)node * HH * C + h * C + ch];
  int p = r0;
  int srcN = 0;
  float evN = 0.f;
  if (p < r1) { srcN = esrc[p]; evN = evals[(size_t)p * HH + h]; }
  while (p < r1) {
    int src = srcN;
    float ev = evN;
    ++p;
    if (p < r1) { srcN = esrc[p]; evN = evals[(size_t)p * HH + h]; }
    float pv = __expf(ev - m);
    float hv = HF[(size_t)src * HH * C + h * C + ch];
    s += pv;
    acc += pv * hv;
  }
  float v = acc / (s + 1e-16f) + bias[h * C + ch];
  if (DO_ELU) v = v > 0.f ? v : expm1f(v);
  if (act) OUT[(size_t)node * HH * C + h * C + ch] = v;
}

// ---------------- launch ----------------

extern "C" void kernel_launch(void* const* d_in, const int* in_sizes, int n_in,
                              void* d_out, int out_size, void* d_ws, size_t ws_size,
                              hipStream_t stream) {
  const float* x     = (const float*)d_in[0];
  const int*   ei    = (const int*)d_in[1];
  const float* W1    = (const float*)d_in[2];
  const float* asrc1 = (const float*)d_in[3];
  const float* adst1 = (const float*)d_in[4];
  const float* b1    = (const float*)d_in[5];
  const float* W2    = (const float*)d_in[6];
  const float* asrc2 = (const float*)d_in[7];
  const float* adst2 = (const float*)d_in[8];
  const float* b2    = (const float*)d_in[9];
  const float* W3    = (const float*)d_in[10];
  const float* asrc3 = (const float*)d_in[11];
  const float* adst3 = (const float*)d_in[12];
  const float* b3    = (const float*)d_in[13];
  float* outf = (float*)d_out;

  const int n = in_sizes[0] / 32;   // 10000
  const int E = in_sizes[1] / 2;    // 160000

  // workspace layout (256B-aligned slices)
  char* ws = (char*)d_ws;
  size_t off = 0;
  auto alloc = [&](size_t bytes) {
    size_t o = off;
    off = (off + bytes + 255) & ~(size_t)255;
    return ws + o;
  };
  int* deg     = (int*)alloc((size_t)n * 4);
  int* rowptr  = (int*)alloc((size_t)(n + 1) * 4);
  int* cursor  = (int*)alloc((size_t)n * 4);
  int* esrc    = (int*)alloc((size_t)E * 4);
  int* edst    = (int*)alloc((size_t)E * 4);
  float* evals = (float*)alloc((size_t)E * 8 * 4);   // reused by all layers
  float* selfe = (float*)alloc((size_t)n * 8 * 4);   // reused by all layers
  float* als   = (float*)alloc((size_t)n * 8 * 4);   // reused
  float* ald   = (float*)alloc((size_t)n * 8 * 4);   // reused
  float* h1    = (float*)alloc((size_t)n * 64 * 4);
  float* x1    = (float*)alloc((size_t)n * 64 * 4);
  float* h2    = (float*)alloc((size_t)n * 512 * 4);
  float* x2    = (float*)alloc((size_t)n * 512 * 4);
  float* h3    = (float*)alloc((size_t)n * 6 * 4);

  // ---- CSR build (shared by all layers) ----
  hipMemsetAsync(deg, 0, (size_t)n * 4, stream);
  count_deg<<<(E + 255) / 256, 256, 0, stream>>>(ei, deg, E);
  scan_k<<<1, 1024, 0, stream>>>(deg, rowptr, cursor, n);
  fill_edges<<<(E + 255) / 256, 256, 0, stream>>>(ei, cursor, esrc, edst, E);

  // ---- layer 1: 32 -> 8x8, concat, ELU ----
  gemm8<32, 64><<<(n * 8 + 255) / 256, 256, 0, stream>>>(x, W1, h1, n);
  logits_k<8, 8><<<(n * 8 + 255) / 256, 256, 0, stream>>>(h1, asrc1, adst1, als, ald, selfe, n);
  edge_e<8><<<(E + 255) / 256, 256, 0, stream>>>(esrc, edst, als, ald, evals, E);
  gather_k<8, 8, 8, true><<<((size_t)n * 64 + 255) / 256, 256, 0, stream>>>(
      h1, evals, selfe, b1, rowptr, esrc, x1, n);

  // ---- layer 2: 64 -> 8x64, concat, ELU ----
  gemm_nb<64, 512, 8><<<(n + 7) / 8, 64, 0, stream>>>(x1, W2, h2, n);
  logits_k<8, 64><<<(n * 8 + 255) / 256, 256, 0, stream>>>(h2, asrc2, adst2, als, ald, selfe, n);
  edge_e<8><<<(E + 255) / 256, 256, 0, stream>>>(esrc, edst, als, ald, evals, E);
  gather_k<8, 64, 1, true><<<((size_t)n * 8 * 64 + 255) / 256, 256, 0, stream>>>(
      h2, evals, selfe, b2, rowptr, esrc, x2, n);

  // ---- layer 3: 512 -> 6, 1 head, mean (=identity over 1 head), no ELU ----
  gemm_l3<<<n, 64, 0, stream>>>(x2, W3, h3, n);
  logits_k<1, 6><<<(n + 255) / 256, 256, 0, stream>>>(h3, asrc3, adst3, als, ald, selfe, n);
  edge_e<1><<<(E + 255) / 256, 256, 0, stream>>>(esrc, edst, als, ald, evals, E);
  gather_k<1, 6, 1, false><<<((size_t)n * 64 + 255) / 256, 256, 0, stream>>>(
      h3, evals, selfe, b3, rowptr, esrc, outf, n);
}

// Round 3
// 308.991 us; speedup vs baseline: 1.0984x; 1.0984x over previous
//
#include <hip/hip_runtime.h>
#include <hip/hip_bf16.h>
#include <math.h>

// ---------------------------------------------------------------------------
// 3-layer GAT (PyG GATConv semantics, self-loops, eval mode).
// Round-3 structure: fully precompute normalized attention weights alpha
// (transposed [head][E] for sequential float4 reads), then aggregation is a
// pure alpha-weighted SpMM gather: per edge = shift + load + fma. No expf,
// no max pass, no rescale in the hot loop.
// ---------------------------------------------------------------------------

#define NEG_SLOPE 0.2f

// ---------------- CSR build ----------------

__global__ __launch_bounds__(256) void count_deg(const int* __restrict__ ei,
                                                 int* __restrict__ deg, int E) {
  int e = blockIdx.x * blockDim.x + threadIdx.x;
  if (e < E) atomicAdd(&deg[ei[E + e]], 1);  // ei[E+e] = dst
}

__global__ __launch_bounds__(1024) void scan_k(const int* __restrict__ deg,
                                               int* __restrict__ rowptr,
                                               int* __restrict__ cursor, int n) {
  __shared__ int part[1024];
  int t = threadIdx.x;
  int chunk = (n + 1023) >> 10;
  int lo = t * chunk;
  int hi = min(lo + chunk, n);
  int s = 0;
  for (int i = lo; i < hi; ++i) s += deg[i];
  part[t] = s;
  __syncthreads();
  for (int off = 1; off < 1024; off <<= 1) {
    int v = (t >= off) ? part[t - off] : 0;
    __syncthreads();
    part[t] += v;
    __syncthreads();
  }
  int run = (t == 0) ? 0 : part[t - 1];
  for (int i = lo; i < hi; ++i) {
    rowptr[i] = run;
    cursor[i] = run;
    run += deg[i];
  }
  if (t == 1023) rowptr[n] = part[1023];
}

__global__ __launch_bounds__(256) void fill_edges(const int* __restrict__ ei,
                                                  int* __restrict__ cursor,
                                                  int* __restrict__ esrc,
                                                  int* __restrict__ edst, int E) {
  int e = blockIdx.x * blockDim.x + threadIdx.x;
  if (e < E) {
    int d = ei[E + e];
    int pos = atomicAdd(&cursor[d], 1);
    esrc[pos] = ei[e];  // src
    edst[pos] = d;
  }
}

// ---------------- GEMMs ----------------

template <int K, int N>
__global__ __launch_bounds__(256) void gemm8(const float* __restrict__ X,
                                             const float* __restrict__ W,
                                             float* __restrict__ H, int n) {
  int idx = blockIdx.x * blockDim.x + threadIdx.x;
  constexpr int PER = N / 8;
  int node = idx / PER;
  int c0 = (idx % PER) * 8;
  if (node >= n) return;
  float a0 = 0.f, a1 = 0.f, a2 = 0.f, a3 = 0.f, a4 = 0.f, a5 = 0.f, a6 = 0.f, a7 = 0.f;
  const float* xr = X + (size_t)node * K;
#pragma unroll 4
  for (int k = 0; k < K; ++k) {
    float xv = xr[k];
    const float4 w0 = *reinterpret_cast<const float4*>(&W[(size_t)k * N + c0]);
    const float4 w1 = *reinterpret_cast<const float4*>(&W[(size_t)k * N + c0 + 4]);
    a0 += xv * w0.x; a1 += xv * w0.y; a2 += xv * w0.z; a3 += xv * w0.w;
    a4 += xv * w1.x; a5 += xv * w1.y; a6 += xv * w1.z; a7 += xv * w1.w;
  }
  float4* o = reinterpret_cast<float4*>(&H[(size_t)node * N + c0]);
  o[0] = make_float4(a0, a1, a2, a3);
  o[1] = make_float4(a4, a5, a6, a7);
}

// Layer 2: wave handles NB nodes x all 512 cols (8/lane); 256-thr blocks
// (4 waves) for occupancy. W row reused NB times per wave.
template <int K, int N, int NB>
__global__ __launch_bounds__(256) void gemm_nb(const float* __restrict__ X,
                                               const float* __restrict__ W,
                                               float* __restrict__ H, int n) {
  int w = blockIdx.x * 4 + (threadIdx.x >> 6);
  int lane = threadIdx.x & 63;
  int node0 = w * NB;
  if (node0 >= n) return;
  int c0 = lane * (N / 64);
  float acc[NB][8];
#pragma unroll
  for (int j = 0; j < NB; ++j)
#pragma unroll
    for (int c = 0; c < 8; ++c) acc[j][c] = 0.f;
  for (int k = 0; k < K; ++k) {
    const float4 w0 = *reinterpret_cast<const float4*>(&W[(size_t)k * N + c0]);
    const float4 w1 = *reinterpret_cast<const float4*>(&W[(size_t)k * N + c0 + 4]);
#pragma unroll
    for (int j = 0; j < NB; ++j) {
      int nd = min(node0 + j, n - 1);
      float xv = X[(size_t)nd * K + k];
      acc[j][0] += xv * w0.x; acc[j][1] += xv * w0.y;
      acc[j][2] += xv * w0.z; acc[j][3] += xv * w0.w;
      acc[j][4] += xv * w1.x; acc[j][5] += xv * w1.y;
      acc[j][6] += xv * w1.z; acc[j][7] += xv * w1.w;
    }
  }
#pragma unroll
  for (int j = 0; j < NB; ++j) {
    int nd = node0 + j;
    if (nd >= n) break;
    float4* o = reinterpret_cast<float4*>(&H[(size_t)nd * N + c0]);
    o[0] = make_float4(acc[j][0], acc[j][1], acc[j][2], acc[j][3]);
    o[1] = make_float4(acc[j][4], acc[j][5], acc[j][6], acc[j][7]);
  }
}

// Layer-3 GEMM: X[n,512] @ W[512,6]; wave per node, lane-split K, shuffle reduce.
__global__ __launch_bounds__(64) void gemm_l3(const float* __restrict__ X,
                                              const float* __restrict__ W,
                                              float* __restrict__ H, int n) {
  int node = blockIdx.x;
  int lane = threadIdx.x;
  if (node >= n) return;
  float acc[6] = {0.f, 0.f, 0.f, 0.f, 0.f, 0.f};
  for (int k = lane; k < 512; k += 64) {
    float xv = X[(size_t)node * 512 + k];
#pragma unroll
    for (int c = 0; c < 6; ++c) acc[c] += xv * W[k * 6 + c];
  }
#pragma unroll
  for (int c = 0; c < 6; ++c) {
    float v = acc[c];
    for (int off = 32; off >= 1; off >>= 1) v += __shfl_down(v, off, 64);
    if (lane == 0) H[(size_t)node * 6 + c] = v;
  }
}

// ---------------- logits: als/ald per (node,head) + self-loop logit ----------

template <int HH, int C>
__global__ __launch_bounds__(256) void logits_k(const float* __restrict__ HF,
                                                const float* __restrict__ Asrc,
                                                const float* __restrict__ Adst,
                                                float* __restrict__ als,
                                                float* __restrict__ ald,
                                                float* __restrict__ selfe, int n) {
  int idx = blockIdx.x * blockDim.x + threadIdx.x;
  if (idx >= n * HH) return;
  int node = idx / HH;
  int h = idx - node * HH;
  const float* f = HF + (size_t)node * HH * C + h * C;
  float s0 = 0.f, s1 = 0.f;
  if constexpr (C % 4 == 0) {
#pragma unroll
    for (int c4 = 0; c4 < C / 4; ++c4) {
      float4 v = *reinterpret_cast<const float4*>(&f[c4 * 4]);
      float4 as = *reinterpret_cast<const float4*>(&Asrc[h * C + c4 * 4]);
      float4 ad = *reinterpret_cast<const float4*>(&Adst[h * C + c4 * 4]);
      s0 += v.x * as.x + v.y * as.y + v.z * as.z + v.w * as.w;
      s1 += v.x * ad.x + v.y * ad.y + v.z * ad.z + v.w * ad.w;
    }
  } else {
#pragma unroll
    for (int c = 0; c < C; ++c) {
      float v = f[c];
      s0 += v * Asrc[h * C + c];
      s1 += v * Adst[h * C + c];
    }
  }
  als[idx] = s0;
  ald[idx] = s1;
  float e = s0 + s1;
  selfe[idx] = e > 0.f ? e : NEG_SLOPE * e;
}

// ---------------- per-edge logits, stored TRANSPOSED evt[h][E] --------------

template <int HH>
__global__ __launch_bounds__(256) void edge_e(const int* __restrict__ esrc,
                                              const int* __restrict__ edst,
                                              const float* __restrict__ als,
                                              const float* __restrict__ ald,
                                              float* __restrict__ evt, int E) {
  int e = blockIdx.x * blockDim.x + threadIdx.x;
  if (e >= E) return;
  int s = esrc[e], d = edst[e];
  if constexpr (HH == 8) {
    float4 s0 = *reinterpret_cast<const float4*>(&als[(size_t)s * 8]);
    float4 s1 = *reinterpret_cast<const float4*>(&als[(size_t)s * 8 + 4]);
    float4 d0 = *reinterpret_cast<const float4*>(&ald[(size_t)d * 8]);
    float4 d1 = *reinterpret_cast<const float4*>(&ald[(size_t)d * 8 + 4]);
    float v[8] = {s0.x + d0.x, s0.y + d0.y, s0.z + d0.z, s0.w + d0.w,
                  s1.x + d1.x, s1.y + d1.y, s1.z + d1.z, s1.w + d1.w};
#pragma unroll
    for (int h = 0; h < 8; ++h)
      evt[(size_t)h * E + e] = v[h] > 0.f ? v[h] : NEG_SLOPE * v[h];
  } else {
#pragma unroll
    for (int h = 0; h < HH; ++h) {
      float v = als[(size_t)s * HH + h] + ald[(size_t)d * HH + h];
      evt[(size_t)h * E + e] = v > 0.f ? v : NEG_SLOPE * v;
    }
  }
}

// ---------------- per-(node,head) softmax stats -----------------------------
// grid: (ceil(n/256), HH). Outputs m, rcp_s, and normalized self-loop alpha.

template <int HH>
__global__ __launch_bounds__(256) void msum_k(const float* __restrict__ evt,
                                              const float* __restrict__ selfe,
                                              const int* __restrict__ rowptr,
                                              float* __restrict__ am,
                                              float* __restrict__ ars,
                                              float* __restrict__ asel,
                                              int n, int E) {
  int node = blockIdx.x * 256 + threadIdx.x;
  int h = blockIdx.y;
  if (node >= n) return;
  int r0 = rowptr[node], r1 = rowptr[node + 1];
  const float* row = evt + (size_t)h * E;
  float e0 = selfe[node * HH + h];
  float m = e0;
  for (int p = r0; p < r1; ++p) m = fmaxf(m, row[p]);
  float s = __expf(e0 - m);
  float a0 = s;
  for (int p = r0; p < r1; ++p) s += __expf(row[p] - m);
  float rs = 1.f / (s + 1e-16f);
  int idx = node * HH + h;
  am[idx] = m;
  ars[idx] = rs;
  asel[idx] = a0 * rs;
}

// ---------------- per-edge normalized alpha (in place over evt) -------------

template <int HH>
__global__ __launch_bounds__(256) void alpha_k(float* __restrict__ evt,
                                               const int* __restrict__ edst,
                                               const float* __restrict__ am,
                                               const float* __restrict__ ars,
                                               int E) {
  int e = blockIdx.x * blockDim.x + threadIdx.x;
  if (e >= E) return;
  int d = edst[e];
#pragma unroll
  for (int h = 0; h < HH; ++h) {
    float v = evt[(size_t)h * E + e];
    evt[(size_t)h * E + e] = __expf(v - am[d * HH + h]) * ars[d * HH + h];
  }
}

// ---------------- aggregates: pure alpha-weighted gather --------------------

// Layer 1: wave per node; lane = (hg=lane>>3 head, ch=lane&7). HF row 256B.
__global__ __launch_bounds__(256) void agg_l1(const float* __restrict__ HF,
                                              const float* __restrict__ alpha,
                                              const float* __restrict__ asel,
                                              const float* __restrict__ bias,
                                              const int* __restrict__ rowptr,
                                              const int* __restrict__ esrc,
                                              float* __restrict__ OUT, int n, int E) {
  int node = blockIdx.x * 4 + (threadIdx.x >> 6);
  int lane = threadIdx.x & 63;
  if (node >= n) return;
  int hg = lane >> 3;
  const float* arow = alpha + (size_t)hg * E;
  float acc = asel[node * 8 + hg] * HF[((unsigned)node << 6) + lane];
  int r0 = rowptr[node], r1 = rowptr[node + 1];
  int p = r0;
  int pa = min(r1, (r0 + 3) & ~3);
  for (; p < pa; ++p) acc += arow[p] * HF[((unsigned)esrc[p] << 6) + lane];
  if (p + 4 <= r1) {
    int4 s4 = *reinterpret_cast<const int4*>(&esrc[p]);
    float4 a4 = *reinterpret_cast<const float4*>(&arow[p]);
    for (;;) {
      int4 sc = s4;
      float4 ac = a4;
      int pn = p + 4;
      bool more = pn + 4 <= r1;
      if (more) {
        s4 = *reinterpret_cast<const int4*>(&esrc[pn]);
        a4 = *reinterpret_cast<const float4*>(&arow[pn]);
      }
      acc += ac.x * HF[((unsigned)sc.x << 6) + lane];
      acc += ac.y * HF[((unsigned)sc.y << 6) + lane];
      acc += ac.z * HF[((unsigned)sc.z << 6) + lane];
      acc += ac.w * HF[((unsigned)sc.w << 6) + lane];
      p = pn;
      if (!more) break;
    }
  }
  for (; p < r1; ++p) acc += arow[p] * HF[((unsigned)esrc[p] << 6) + lane];
  float v = acc + bias[lane];
  v = v > 0.f ? v : expm1f(v);
  OUT[((unsigned)node << 6) + lane] = v;
}

// Layer 2: wave per (node,head); lane = channel (64). HF row slice 256B.
__global__ __launch_bounds__(256) void agg_l2(const float* __restrict__ HF,
                                              const float* __restrict__ alpha,
                                              const float* __restrict__ asel,
                                              const float* __restrict__ bias,
                                              const int* __restrict__ rowptr,
                                              const int* __restrict__ esrc,
                                              float* __restrict__ OUT, int n, int E) {
  int w = blockIdx.x * 4 + (threadIdx.x >> 6);
  int lane = threadIdx.x & 63;
  int node = w >> 3;
  int h = w & 7;
  if (node >= n) return;
  unsigned coloff = ((unsigned)h << 6) + lane;
  const float* arow = alpha + (size_t)h * E;
  float acc = asel[node * 8 + h] * HF[((unsigned)node << 9) + coloff];
  int r0 = rowptr[node], r1 = rowptr[node + 1];
  int p = r0;
  int pa = min(r1, (r0 + 3) & ~3);
  for (; p < pa; ++p) acc += arow[p] * HF[((unsigned)esrc[p] << 9) + coloff];
  if (p + 4 <= r1) {
    int4 s4 = *reinterpret_cast<const int4*>(&esrc[p]);
    float4 a4 = *reinterpret_cast<const float4*>(&arow[p]);
    for (;;) {
      int4 sc = s4;
      float4 ac = a4;
      int pn = p + 4;
      bool more = pn + 4 <= r1;
      if (more) {
        s4 = *reinterpret_cast<const int4*>(&esrc[pn]);
        a4 = *reinterpret_cast<const float4*>(&arow[pn]);
      }
      acc += ac.x * HF[((unsigned)sc.x << 9) + coloff];
      acc += ac.y * HF[((unsigned)sc.y << 9) + coloff];
      acc += ac.z * HF[((unsigned)sc.z << 9) + coloff];
      acc += ac.w * HF[((unsigned)sc.w << 9) + coloff];
      p = pn;
      if (!more) break;
    }
  }
  for (; p < r1; ++p) acc += arow[p] * HF[((unsigned)esrc[p] << 9) + coloff];
  float v = acc + bias[coloff];
  v = v > 0.f ? v : expm1f(v);
  OUT[((unsigned)node << 9) + coloff] = v;
}

// Layer 3: wave per node; lanes 0..5 = channels; no ELU.
__global__ __launch_bounds__(256) void agg_l3(const float* __restrict__ HF,
                                              const float* __restrict__ alpha,
                                              const float* __restrict__ asel,
                                              const float* __restrict__ bias,
                                              const int* __restrict__ rowptr,
                                              const int* __restrict__ esrc,
                                              float* __restrict__ OUT, int n, int E) {
  int node = blockIdx.x * 4 + (threadIdx.x >> 6);
  int lane = threadIdx.x & 63;
  if (node >= n) return;
  int ch = lane < 6 ? lane : 0;
  float acc = asel[node] * HF[(unsigned)node * 6u + ch];
  int r0 = rowptr[node], r1 = rowptr[node + 1];
  int p = r0;
  int pa = min(r1, (r0 + 3) & ~3);
  for (; p < pa; ++p) acc += alpha[p] * HF[(unsigned)esrc[p] * 6u + ch];
  if (p + 4 <= r1) {
    int4 s4 = *reinterpret_cast<const int4*>(&esrc[p]);
    float4 a4 = *reinterpret_cast<const float4*>(&alpha[p]);
    for (;;) {
      int4 sc = s4;
      float4 ac = a4;
      int pn = p + 4;
      bool more = pn + 4 <= r1;
      if (more) {
        s4 = *reinterpret_cast<const int4*>(&esrc[pn]);
        a4 = *reinterpret_cast<const float4*>(&alpha[pn]);
      }
      acc += ac.x * HF[(unsigned)sc.x * 6u + ch];
      acc += ac.y * HF[(unsigned)sc.y * 6u + ch];
      acc += ac.z * HF[(unsigned)sc.z * 6u + ch];
      acc += ac.w * HF[(unsigned)sc.w * 6u + ch];
      p = pn;
      if (!more) break;
    }
  }
  for (; p < r1; ++p) acc += alpha[p] * HF[(unsigned)esrc[p] * 6u + ch];
  if (lane < 6) OUT[(unsigned)node * 6u + lane] = acc + bias[lane];
}

// ---------------- launch ----------------

extern "C" void kernel_launch(void* const* d_in, const int* in_sizes, int n_in,
                              void* d_out, int out_size, void* d_ws, size_t ws_size,
                              hipStream_t stream) {
  const float* x     = (const float*)d_in[0];
  const int*   ei    = (const int*)d_in[1];
  const float* W1    = (const float*)d_in[2];
  const float* asrc1 = (const float*)d_in[3];
  const float* adst1 = (const float*)d_in[4];
  const float* b1    = (const float*)d_in[5];
  const float* W2    = (const float*)d_in[6];
  const float* asrc2 = (const float*)d_in[7];
  const float* adst2 = (const float*)d_in[8];
  const float* b2    = (const float*)d_in[9];
  const float* W3    = (const float*)d_in[10];
  const float* asrc3 = (const float*)d_in[11];
  const float* adst3 = (const float*)d_in[12];
  const float* b3    = (const float*)d_in[13];
  float* outf = (float*)d_out;

  const int n = in_sizes[0] / 32;   // 10000
  const int E = in_sizes[1] / 2;    // 160000

  char* ws = (char*)d_ws;
  size_t off = 0;
  auto alloc = [&](size_t bytes) {
    size_t o = off;
    off = (off + bytes + 255) & ~(size_t)255;
    return ws + o;
  };
  int* deg     = (int*)alloc((size_t)n * 4);
  int* rowptr  = (int*)alloc((size_t)(n + 1) * 4);
  int* cursor  = (int*)alloc((size_t)n * 4);
  int* esrc    = (int*)alloc((size_t)E * 4);
  int* edst    = (int*)alloc((size_t)E * 4);
  float* evt   = (float*)alloc((size_t)E * 8 * 4);   // transposed logits->alpha
  float* selfe = (float*)alloc((size_t)n * 8 * 4);
  float* als   = (float*)alloc((size_t)n * 8 * 4);
  float* ald   = (float*)alloc((size_t)n * 8 * 4);
  float* am    = (float*)alloc((size_t)n * 8 * 4);
  float* ars   = (float*)alloc((size_t)n * 8 * 4);
  float* asel  = (float*)alloc((size_t)n * 8 * 4);
  float* h1    = (float*)alloc((size_t)n * 64 * 4);
  float* x1    = (float*)alloc((size_t)n * 64 * 4);
  float* h2    = (float*)alloc((size_t)n * 512 * 4);
  float* x2    = (float*)alloc((size_t)n * 512 * 4);
  float* h3    = (float*)alloc((size_t)n * 6 * 4);

  // ---- CSR build (shared by all layers) ----
  hipMemsetAsync(deg, 0, (size_t)n * 4, stream);
  count_deg<<<(E + 255) / 256, 256, 0, stream>>>(ei, deg, E);
  scan_k<<<1, 1024, 0, stream>>>(deg, rowptr, cursor, n);
  fill_edges<<<(E + 255) / 256, 256, 0, stream>>>(ei, cursor, esrc, edst, E);

  dim3 msg((n + 255) / 256, 8);
  dim3 msg1((n + 255) / 256, 1);

  // ---- layer 1: 32 -> 8x8, concat, ELU ----
  gemm8<32, 64><<<(n * 8 + 255) / 256, 256, 0, stream>>>(x, W1, h1, n);
  logits_k<8, 8><<<(n * 8 + 255) / 256, 256, 0, stream>>>(h1, asrc1, adst1, als, ald, selfe, n);
  edge_e<8><<<(E + 255) / 256, 256, 0, stream>>>(esrc, edst, als, ald, evt, E);
  msum_k<8><<<msg, 256, 0, stream>>>(evt, selfe, rowptr, am, ars, asel, n, E);
  alpha_k<8><<<(E + 255) / 256, 256, 0, stream>>>(evt, edst, am, ars, E);
  agg_l1<<<(n + 3) / 4, 256, 0, stream>>>(h1, evt, asel, b1, rowptr, esrc, x1, n, E);

  // ---- layer 2: 64 -> 8x64, concat, ELU ----
  gemm_nb<64, 512, 4><<<(n + 15) / 16, 256, 0, stream>>>(x1, W2, h2, n);
  logits_k<8, 64><<<(n * 8 + 255) / 256, 256, 0, stream>>>(h2, asrc2, adst2, als, ald, selfe, n);
  edge_e<8><<<(E + 255) / 256, 256, 0, stream>>>(esrc, edst, als, ald, evt, E);
  msum_k<8><<<msg, 256, 0, stream>>>(evt, selfe, rowptr, am, ars, asel, n, E);
  alpha_k<8><<<(E + 255) / 256, 256, 0, stream>>>(evt, edst, am, ars, E);
  agg_l2<<<(n * 8 + 3) / 4, 256, 0, stream>>>(h2, evt, asel, b2, rowptr, esrc, x2, n, E);

  // ---- layer 3: 512 -> 6, 1 head, no ELU ----
  gemm_l3<<<n, 64, 0, stream>>>(x2, W3, h3, n);
  logits_k<1, 6><<<(n + 255) / 256, 256, 0, stream>>>(h3, asrc3, adst3, als, ald, selfe, n);
  edge_e<1><<<(E + 255) / 256, 256, 0, stream>>>(esrc, edst, als, ald, evt, E);
  msum_k<1><<<msg1, 256, 0, stream>>>(evt, selfe, rowptr, am, ars, asel, n, E);
  alpha_k<1><<<(E + 255) / 256, 256, 0, stream>>>(evt, edst, am, ars, E);
  agg_l3<<<(n + 3) / 4, 256, 0, stream>>>(h3, evt, asel, b3, rowptr, esrc, outf, n, E);
}